// Round 4
// baseline (178.139 us; speedup 1.0000x reference)
//
#include <hip/hip_runtime.h>
#include <hip/hip_bf16.h>
#include <math.h>

#define S_LEN 4096
#define NH    8

typedef __attribute__((ext_vector_type(8))) short bf16x8;
typedef __attribute__((ext_vector_type(4))) short bf16x4;
typedef __attribute__((ext_vector_type(4))) float f32x4;

#define QSCALE 0.18033688011112042f   // 0.125 * log2(e): scores land in exp2 domain

// fp32 -> bf16 round-to-nearest-even (scalar)
__device__ __forceinline__ short f2bf(float f) {
    union { float f; unsigned u; } v; v.f = f;
    unsigned r = v.u + 0x7fffu + ((v.u >> 16) & 1u);
    return (short)(r >> 16);
}

// packed 2x fp32 -> bf16 (v_cvt_pk_bf16_f32 on gfx950)
__device__ __forceinline__ int pk2(float a, float b) {
    __hip_bfloat162 t = __float22bfloat162_rn(make_float2(a, b));
    union { __hip_bfloat162 h; int i; } u; u.h = t;
    return u.i;
}

// async 16B global->LDS; HW writes lane i's 16B to ldsbase + i*16
__device__ __forceinline__ void gload16(const void* g, void* l) {
    __builtin_amdgcn_global_load_lds(
        (const __attribute__((address_space(1))) unsigned*)g,
        (__attribute__((address_space(3))) unsigned*)l, 16, 0, 0);
}

// ---------------------------------------------------------------------------
// Stage a 64x64 bf16 tile into an 8KB LDS tile with XOR-swizzled 16B column
// groups: phys(row, cg) = row*128B + ((cg ^ (row&7)) * 16B). Swizzle applied
// on the GLOBAL source address so wave-uniform-base global_load_lds lands
// data where frag() expects.
// ---------------------------------------------------------------------------
__device__ __forceinline__ void stage_tile(const short* gsrc, size_t gstride,
                                           short* tile, int t)
{
    const int wave = t >> 6, lane = t & 63;
    const int sub = lane >> 3;
    const int cg  = (lane & 7) ^ sub;
#pragma unroll
    for (int j = 0; j < 2; ++j) {
        const int chunk = wave * 2 + j;
        const int row = chunk * 8 + sub;
        gload16(gsrc + (size_t)row * gstride + cg * 8, tile + chunk * 512);
    }
}

__device__ __forceinline__ bf16x8 frag(const short* tile, int row, int cg) {
    return *(const bf16x8*)&tile[row * 64 + ((cg ^ (row & 7)) << 3)];
}

// ---------------------------------------------------------------------------
// 64x64-tile MFMA GEMM mainloop, K=512, double-buffered global_load_lds.
// ---------------------------------------------------------------------------
__device__ __forceinline__ void gemm_mainloop_512(
    const short* __restrict__ Arow, const short* __restrict__ Brow,
    short* As, short* Bs, f32x4 acc[4], int t)
{
    const int wave = t >> 6, lane = t & 63, n16 = lane & 15, quad = lane >> 4;
    stage_tile(Arow, 512, As, t);
    stage_tile(Brow, 512, Bs, t);
    __syncthreads();
    for (int c = 0; c < 8; ++c) {
        const int cur = c & 1;
        if (c < 7) {
            stage_tile(Arow + (c + 1) * 64, 512, As + (1 - cur) * 4096, t);
            stage_tile(Brow + (c + 1) * 64, 512, Bs + (1 - cur) * 4096, t);
        }
        const short* as = As + cur * 4096;
        const short* bs = Bs + cur * 4096;
#pragma unroll
        for (int kh = 0; kh < 2; ++kh) {
            const bf16x8 a = frag(as, wave * 16 + n16, kh * 4 + quad);
#pragma unroll
            for (int nt = 0; nt < 4; ++nt) {
                const bf16x8 b = frag(bs, nt * 16 + n16, kh * 4 + quad);
                acc[nt] = __builtin_amdgcn_mfma_f32_16x16x32_bf16(a, b, acc[nt], 0, 0, 0);
            }
        }
        __syncthreads();
    }
}

// ---------------------------------------------------------------------------
// Prep: x->bf16; weight transposes via coalesced LDS tiles.
// ---------------------------------------------------------------------------
__global__ __launch_bounds__(256) void prep_kernel(
    const float* __restrict__ x,
    const float* __restrict__ Wq, const float* __restrict__ Wk,
    const float* __restrict__ Wv, const float* __restrict__ Wo,
    short* __restrict__ xb, short* __restrict__ Wqkvt, short* __restrict__ Wot)
{
    __shared__ short T[64 * 66];
    const int b = blockIdx.x, t = threadIdx.x;
    if (b < 1024) {
        const size_t idx = (size_t)b * 2048 + t * 8;
        const float4 a = *(const float4*)&x[idx];
        const float4 c = *(const float4*)&x[idx + 4];
        bf16x8 o;
        o[0] = f2bf(a.x); o[1] = f2bf(a.y); o[2] = f2bf(a.z); o[3] = f2bf(a.w);
        o[4] = f2bf(c.x); o[5] = f2bf(c.y); o[6] = f2bf(c.z); o[7] = f2bf(c.w);
        *(bf16x8*)&xb[idx] = o;
        return;
    }
    const int c4 = (t & 15) * 4, rsub = t >> 4;
    const int orow = t >> 2, oc16 = (t & 3) * 16;
    if (b < 1216) {
        const int jj = b - 1024, g = jj >> 3, kb = jj & 7;
        const int which = g >> 3, h = g & 7;
        const float* W = ((which == 0) ? Wq : (which == 1) ? Wk : Wv) + (size_t)h * 512 * 64;
#pragma unroll
        for (int p = 0; p < 4; ++p) {
            const int row = p * 16 + rsub;
            const float4 v = *(const float4*)&W[(size_t)(kb * 64 + row) * 64 + c4];
            T[(c4 + 0) * 66 + row] = f2bf(v.x);
            T[(c4 + 1) * 66 + row] = f2bf(v.y);
            T[(c4 + 2) * 66 + row] = f2bf(v.z);
            T[(c4 + 3) * 66 + row] = f2bf(v.w);
        }
        __syncthreads();
        short* O = &Wqkvt[((size_t)g * 64 + orow) * 512 + kb * 64];
        *(bf16x8*)&O[oc16]     = *(const bf16x8*)&T[orow * 66 + oc16];
        *(bf16x8*)&O[oc16 + 8] = *(const bf16x8*)&T[orow * 66 + oc16 + 8];
    } else {
        const int jj = b - 1216, h = jj >> 3, nb = jj & 7;
        const float* W = Wo + (size_t)h * 64 * 512;
#pragma unroll
        for (int p = 0; p < 4; ++p) {
            const int row = p * 16 + rsub;
            const float4 v = *(const float4*)&W[(size_t)row * 512 + nb * 64 + c4];
            T[(c4 + 0) * 66 + row] = f2bf(v.x);
            T[(c4 + 1) * 66 + row] = f2bf(v.y);
            T[(c4 + 2) * 66 + row] = f2bf(v.z);
            T[(c4 + 3) * 66 + row] = f2bf(v.w);
        }
        __syncthreads();
        short* O = &Wot[((size_t)nb * 64 + orow) * 512 + h * 64];
        *(bf16x8*)&O[oc16]     = *(const bf16x8*)&T[orow * 66 + oc16];
        *(bf16x8*)&O[oc16 + 8] = *(const bf16x8*)&T[orow * 66 + oc16 + 8];
    }
}

// ---------------------------------------------------------------------------
// QKV projection. Q pre-scaled by QSCALE; Q,K stored [h][s][64]; V stored
// transposed [h][d][s] via LDS bounce.
// ---------------------------------------------------------------------------
__global__ __launch_bounds__(256) void qkv_gemm_kernel(
    const short* __restrict__ xb, const short* __restrict__ Wqkvt,
    short* __restrict__ Qg, short* __restrict__ Kg, short* __restrict__ Vtg)
{
    __shared__ short smem[16384];
    short* As = smem;
    short* Bs = smem + 8192;
    const int sblk = blockIdx.x, g = blockIdx.y;
    const int which = g >> 3, h = g & 7;
    const int t = threadIdx.x;
    const int wave = t >> 6, lane = t & 63, n16 = lane & 15, quad = lane >> 4;

    f32x4 acc[4] = {{0,0,0,0},{0,0,0,0},{0,0,0,0},{0,0,0,0}};
    gemm_mainloop_512(xb + (size_t)sblk * 64 * 512, Wqkvt + (size_t)g * 64 * 512,
                      As, Bs, acc, t);

    if (which < 2) {
        const float scale = (which == 0) ? QSCALE : 1.0f;
        short* O = ((which == 0) ? Qg : Kg) + (size_t)h * S_LEN * 64;
#pragma unroll
        for (int nt = 0; nt < 4; ++nt)
#pragma unroll
            for (int r = 0; r < 4; ++r) {
                const int s = sblk * 64 + wave * 16 + quad * 4 + r;
                O[(size_t)s * 64 + nt * 16 + n16] = f2bf(acc[nt][r] * scale);
            }
    } else {
        __syncthreads();
        short* Tr = smem;
#pragma unroll
        for (int nt = 0; nt < 4; ++nt)
#pragma unroll
            for (int r = 0; r < 4; ++r)
                Tr[(nt * 16 + n16) * 66 + wave * 16 + quad * 4 + r] = f2bf(acc[nt][r]);
        __syncthreads();
        short* O = Vtg + (size_t)h * 64 * S_LEN + sblk * 64;
        const int r4 = t >> 2, c16 = (t & 3) * 16;
        *(bf16x8*)&O[(size_t)r4 * S_LEN + c16]     = *(const bf16x8*)&Tr[r4 * 66 + c16];
        *(bf16x8*)&O[(size_t)r4 * S_LEN + c16 + 8] = *(const bf16x8*)&Tr[r4 * 66 + c16 + 8];
    }
}

// ---------------------------------------------------------------------------
// Output projection: vals bf16 [4096][512] x Wot[n][c] -> out fp32.
// ---------------------------------------------------------------------------
__global__ __launch_bounds__(256) void out_gemm_kernel(
    const short* __restrict__ vals, const short* __restrict__ Wot, float* __restrict__ out)
{
    __shared__ short smem[16384];
    short* As = smem;
    short* Bs = smem + 8192;
    const int sblk = blockIdx.x, g = blockIdx.y;
    const int t = threadIdx.x;
    const int wave = t >> 6, lane = t & 63, n16 = lane & 15, quad = lane >> 4;

    f32x4 acc[4] = {{0,0,0,0},{0,0,0,0},{0,0,0,0},{0,0,0,0}};
    gemm_mainloop_512(vals + (size_t)sblk * 64 * 512, Wot + (size_t)g * 64 * 512,
                      As, Bs, acc, t);

#pragma unroll
    for (int nt = 0; nt < 4; ++nt)
#pragma unroll
        for (int r = 0; r < 4; ++r) {
            const int s = sblk * 64 + wave * 16 + quad * 4 + r;
            out[(size_t)s * 512 + g * 64 + nt * 16 + n16] = acc[nt][r];
        }
}

// ---------------------------------------------------------------------------
// Flash attention, causal, STATIC-REFERENCE softmax (p = exp2(sc), no max,
// no rescale — shift-invariance makes this exact; score bounds keep exp2 in
// fp32 range). Transposed MFMA formulation:
//   Sc^T[key][q] = K x Q^T ;  O^T[v][q] += V^T x P ;  l via ones-row MFMA.
// k-range of each (h,qb) split into <=16-step chunks; partials combined by
// fp32 atomics into zeroed Oacc/Lacc; norm_kernel divides and packs bf16.
// Grid 1280 = 8 h x 160 chunks; big chunks dispatch first (c reversed);
// h = id&7 pins each head to one XCD.
// ---------------------------------------------------------------------------
__global__ __launch_bounds__(256, 4) void attn_kernel(
    const short* __restrict__ Qg, const short* __restrict__ Kg,
    const short* __restrict__ Vtg, float* __restrict__ Oacc, float* __restrict__ Lacc)
{
    __shared__ short Ks[2][4096];
    __shared__ short Vs[2][4096];
    __shared__ short Ps[4096];             // [q][key^sw], row stride 64

    const int id = blockIdx.x;
    const int h  = id & 7;
    const int c  = 159 - (id >> 3);        // reversed: largest chunks first
    int qb, j;
    if (c < 16)      { qb = c;                  j = 0; }
    else if (c < 48) { qb = 16 + ((c - 16) >> 1); j = (c - 16) & 1; }
    else if (c < 96) { qb = 32 + (c - 48) / 3;    j = (c - 48) % 3; }
    else             { qb = 48 + ((c - 96) >> 2); j = (c - 96) & 3; }
    const int k0   = j * 16;
    const int kend = min(k0 + 16, qb + 1);

    const short* Kh  = Kg  + (size_t)h * S_LEN * 64;
    const short* Vth = Vtg + (size_t)h * 64 * S_LEN;

    const int t = threadIdx.x;
    const int wave = t >> 6, lane = t & 63, n16 = lane & 15, quad = lane >> 4;
    const int qrow = wave * 16 + n16;      // this lane's q (block-local)
    const int sw   = (qrow & 7) << 3;      // Ps key-index swizzle

    // Q B-fragments, loop-invariant, direct from global
    const short* Qr = Qg + (size_t)h * S_LEN * 64 + (size_t)(qb * 64 + qrow) * 64;
    const bf16x8 bq0 = *(const bf16x8*)&Qr[quad * 8];
    const bf16x8 bq1 = *(const bf16x8*)&Qr[32 + quad * 8];

    // all-ones A fragment for l accumulation (bf16 1.0 = 0x3F80)
    bf16x8 ones;
#pragma unroll
    for (int i = 0; i < 8; ++i) ones[i] = (short)0x3F80;

    f32x4 oacc[4] = {{0,0,0,0},{0,0,0,0},{0,0,0,0},{0,0,0,0}};
    f32x4 lacc = {0, 0, 0, 0};

    stage_tile(Kh + (size_t)k0 * 64 * 64, 64, Ks[0], t);
    stage_tile(Vth + k0 * 64, S_LEN, Vs[0], t);
    __syncthreads();

    for (int kb = k0; kb < kend; ++kb) {
        const int cur = (kb - k0) & 1;
        if (kb + 1 < kend) {               // async prefetch into other buffer
            stage_tile(Kh + (size_t)(kb + 1) * 64 * 64, 64, Ks[1 - cur], t);
            stage_tile(Vth + (kb + 1) * 64, S_LEN, Vs[1 - cur], t);
        }

        // Sc^T = K x Q^T
        f32x4 sc[4] = {{0,0,0,0},{0,0,0,0},{0,0,0,0},{0,0,0,0}};
#pragma unroll
        for (int kh = 0; kh < 2; ++kh) {
            const bf16x8 bq = kh ? bq1 : bq0;
#pragma unroll
            for (int mt = 0; mt < 4; ++mt) {
                const bf16x8 a = frag(Ks[cur], mt * 16 + n16, kh * 4 + quad);
                sc[mt] = __builtin_amdgcn_mfma_f32_16x16x32_bf16(a, bq, sc[mt], 0, 0, 0);
            }
        }

        if (kb == qb) {                    // causal mask, diagonal block only
#pragma unroll
            for (int mt = 0; mt < 4; ++mt) {
                const int key0 = mt * 16 + quad * 4;
#pragma unroll
                for (int r = 0; r < 4; ++r)
                    if (key0 + r > qrow) sc[mt][r] = -1e30f;
            }
        }

        // p = exp2(sc); packed bf16 straight to wave-local Ps
#pragma unroll
        for (int mt = 0; mt < 4; ++mt) {
            const float p0 = __builtin_amdgcn_exp2f(sc[mt][0]);
            const float p1 = __builtin_amdgcn_exp2f(sc[mt][1]);
            const float p2 = __builtin_amdgcn_exp2f(sc[mt][2]);
            const float p3 = __builtin_amdgcn_exp2f(sc[mt][3]);
            int2 pk; pk.x = pk2(p0, p1); pk.y = pk2(p2, p3);
            *(int2*)&Ps[qrow * 64 + ((mt * 16 + quad * 4) ^ sw)] = pk;
        }
        __builtin_amdgcn_wave_barrier();   // Ps writes stay above PV reads

        // O^T += V^T x P ; l += ones x P   (Ps rows wave-local, no barrier)
#pragma unroll
        for (int kh = 0; kh < 2; ++kh) {
            const bf16x8 bp = *(const bf16x8*)&Ps[qrow * 64 + ((kh * 32 + quad * 8) ^ sw)];
            lacc = __builtin_amdgcn_mfma_f32_16x16x32_bf16(ones, bp, lacc, 0, 0, 0);
#pragma unroll
            for (int mt = 0; mt < 4; ++mt) {
                const bf16x8 a = frag(Vs[cur], mt * 16 + n16, kh * 4 + quad);
                oacc[mt] = __builtin_amdgcn_mfma_f32_16x16x32_bf16(a, bp, oacc[mt], 0, 0, 0);
            }
        }
        __builtin_amdgcn_wave_barrier();
        __syncthreads();                   // buffer swap + prefetch drain
    }

    // epilogue: accumulate partials into Oacc / Lacc (fp32 atomics)
    const int sg = qb * 64 + qrow;
    if (quad == 0)
        unsafeAtomicAdd(&Lacc[sg * 8 + h], lacc[0]);
#pragma unroll
    for (int mt = 0; mt < 4; ++mt)
#pragma unroll
        for (int r = 0; r < 4; ++r) {
            const int v = mt * 16 + quad * 4 + r;
            unsafeAtomicAdd(&Oacc[(size_t)sg * 512 + h * 64 + v], oacc[mt][r]);
        }
}

// ---------------------------------------------------------------------------
// Normalize: vals[s][c] = bf16( Oacc[s][c] / Lacc[s][c>>6] )
// ---------------------------------------------------------------------------
__global__ __launch_bounds__(256) void norm_kernel(
    const float* __restrict__ Oacc, const float* __restrict__ Lacc,
    short* __restrict__ vals)
{
    const int idx = blockIdx.x * 256 + threadIdx.x;   // 262144 threads
    const int s  = idx >> 6;
    const int c8 = (idx & 63) * 8;
    const float inv = 1.f / Lacc[s * 8 + (c8 >> 6)];
    const float4 a = *(const float4*)&Oacc[(size_t)s * 512 + c8];
    const float4 b = *(const float4*)&Oacc[(size_t)s * 512 + c8 + 4];
    int4 o;
    o.x = pk2(a.x * inv, a.y * inv);
    o.y = pk2(a.z * inv, a.w * inv);
    o.z = pk2(b.x * inv, b.y * inv);
    o.w = pk2(b.z * inv, b.w * inv);
    *(int4*)&vals[(size_t)s * 512 + c8] = o;
}

// ---------------------------------------------------------------------------
// Workspace: shorts region (xb 4MB | Wqkvt 1.5MB | Wot 0.5MB | Qg/Kg/Vtg 4MB
// | vals 4MB) then fp32 Oacc 8MB + Lacc 128KB  ~= 31 MB.
// ---------------------------------------------------------------------------
extern "C" void kernel_launch(void* const* d_in, const int* in_sizes, int n_in,
                              void* d_out, int out_size, void* d_ws, size_t ws_size,
                              hipStream_t stream)
{
    const float* x  = (const float*)d_in[0];
    const float* Wq = (const float*)d_in[1];
    const float* Wk = (const float*)d_in[2];
    const float* Wv = (const float*)d_in[3];
    const float* Wo = (const float*)d_in[4];
    float* out = (float*)d_out;

    short* xb    = (short*)d_ws;
    short* Wqkvt = xb + 2097152;
    short* Wot   = Wqkvt + 786432;
    short* Qg    = Wot + 262144;
    short* Kg    = Qg + 2097152;
    short* Vtg   = Kg + 2097152;
    short* vals  = Vtg + 2097152;
    float* Oacc  = (float*)(vals + 2097152);
    float* Lacc  = Oacc + (size_t)S_LEN * 512;

    hipMemsetAsync(Oacc, 0, ((size_t)S_LEN * 512 + S_LEN * 8) * sizeof(float), stream);
    prep_kernel<<<1280, 256, 0, stream>>>(x, Wq, Wk, Wv, Wo, xb, Wqkvt, Wot);
    qkv_gemm_kernel<<<dim3(64, 24), 256, 0, stream>>>(xb, Wqkvt, Qg, Kg, Vtg);
    attn_kernel<<<1280, 256, 0, stream>>>(Qg, Kg, Vtg, Oacc, Lacc);
    norm_kernel<<<1024, 256, 0, stream>>>(Oacc, Lacc, vals);
    out_gemm_kernel<<<dim3(64, 8), 256, 0, stream>>>(vals, Wot, out);
}

// Round 5
// 134.831 us; speedup vs baseline: 1.3212x; 1.3212x over previous
//
#include <hip/hip_runtime.h>
#include <hip/hip_bf16.h>
#include <math.h>

#define S_LEN 4096
#define NH    8

typedef __attribute__((ext_vector_type(8))) short bf16x8;
typedef __attribute__((ext_vector_type(4))) short bf16x4;
typedef __attribute__((ext_vector_type(4))) float f32x4;

#define QSCALE 0.18033688011112042f   // 0.125 * log2(e): scores land in exp2 domain

// fp32 -> bf16 round-to-nearest-even (scalar)
__device__ __forceinline__ short f2bf(float f) {
    union { float f; unsigned u; } v; v.f = f;
    unsigned r = v.u + 0x7fffu + ((v.u >> 16) & 1u);
    return (short)(r >> 16);
}

// packed 2x fp32 -> bf16 (v_cvt_pk_bf16_f32 on gfx950)
__device__ __forceinline__ int pk2(float a, float b) {
    __hip_bfloat162 t = __float22bfloat162_rn(make_float2(a, b));
    union { __hip_bfloat162 h; int i; } u; u.h = t;
    return u.i;
}

// async 16B global->LDS; HW writes lane i's 16B to ldsbase + i*16
__device__ __forceinline__ void gload16(const void* g, void* l) {
    __builtin_amdgcn_global_load_lds(
        (const __attribute__((address_space(1))) unsigned*)g,
        (__attribute__((address_space(3))) unsigned*)l, 16, 0, 0);
}

// ---------------------------------------------------------------------------
// Stage a 64x64 bf16 tile into an 8KB LDS tile with XOR-swizzled 16B column
// groups: phys(row, cg) = row*128B + ((cg ^ (row&7)) * 16B). Swizzle applied
// on the GLOBAL source address so wave-uniform-base global_load_lds lands
// data where frag() expects.
// ---------------------------------------------------------------------------
__device__ __forceinline__ void stage_tile(const short* gsrc, size_t gstride,
                                           short* tile, int t)
{
    const int wave = t >> 6, lane = t & 63;
    const int sub = lane >> 3;
    const int cg  = (lane & 7) ^ sub;
#pragma unroll
    for (int j = 0; j < 2; ++j) {
        const int chunk = wave * 2 + j;
        const int row = chunk * 8 + sub;
        gload16(gsrc + (size_t)row * gstride + cg * 8, tile + chunk * 512);
    }
}

__device__ __forceinline__ bf16x8 frag(const short* tile, int row, int cg) {
    return *(const bf16x8*)&tile[row * 64 + ((cg ^ (row & 7)) << 3)];
}

// ---------------------------------------------------------------------------
// 64x64-tile MFMA GEMM mainloop, K=512, double-buffered global_load_lds.
// ---------------------------------------------------------------------------
__device__ __forceinline__ void gemm_mainloop_512(
    const short* __restrict__ Arow, const short* __restrict__ Brow,
    short* As, short* Bs, f32x4 acc[4], int t)
{
    const int wave = t >> 6, lane = t & 63, n16 = lane & 15, quad = lane >> 4;
    stage_tile(Arow, 512, As, t);
    stage_tile(Brow, 512, Bs, t);
    __syncthreads();
    for (int c = 0; c < 8; ++c) {
        const int cur = c & 1;
        if (c < 7) {
            stage_tile(Arow + (c + 1) * 64, 512, As + (1 - cur) * 4096, t);
            stage_tile(Brow + (c + 1) * 64, 512, Bs + (1 - cur) * 4096, t);
        }
        const short* as = As + cur * 4096;
        const short* bs = Bs + cur * 4096;
#pragma unroll
        for (int kh = 0; kh < 2; ++kh) {
            const bf16x8 a = frag(as, wave * 16 + n16, kh * 4 + quad);
#pragma unroll
            for (int nt = 0; nt < 4; ++nt) {
                const bf16x8 b = frag(bs, nt * 16 + n16, kh * 4 + quad);
                acc[nt] = __builtin_amdgcn_mfma_f32_16x16x32_bf16(a, b, acc[nt], 0, 0, 0);
            }
        }
        __syncthreads();
    }
}

// ---------------------------------------------------------------------------
// Prep: x->bf16; weight transposes via coalesced LDS tiles.
// ---------------------------------------------------------------------------
__global__ __launch_bounds__(256) void prep_kernel(
    const float* __restrict__ x,
    const float* __restrict__ Wq, const float* __restrict__ Wk,
    const float* __restrict__ Wv, const float* __restrict__ Wo,
    short* __restrict__ xb, short* __restrict__ Wqkvt, short* __restrict__ Wot)
{
    __shared__ short T[64 * 66];
    const int b = blockIdx.x, t = threadIdx.x;
    if (b < 1024) {
        const size_t idx = (size_t)b * 2048 + t * 8;
        const float4 a = *(const float4*)&x[idx];
        const float4 c = *(const float4*)&x[idx + 4];
        bf16x8 o;
        o[0] = f2bf(a.x); o[1] = f2bf(a.y); o[2] = f2bf(a.z); o[3] = f2bf(a.w);
        o[4] = f2bf(c.x); o[5] = f2bf(c.y); o[6] = f2bf(c.z); o[7] = f2bf(c.w);
        *(bf16x8*)&xb[idx] = o;
        return;
    }
    const int c4 = (t & 15) * 4, rsub = t >> 4;
    const int orow = t >> 2, oc16 = (t & 3) * 16;
    if (b < 1216) {
        const int jj = b - 1024, g = jj >> 3, kb = jj & 7;
        const int which = g >> 3, h = g & 7;
        const float* W = ((which == 0) ? Wq : (which == 1) ? Wk : Wv) + (size_t)h * 512 * 64;
#pragma unroll
        for (int p = 0; p < 4; ++p) {
            const int row = p * 16 + rsub;
            const float4 v = *(const float4*)&W[(size_t)(kb * 64 + row) * 64 + c4];
            T[(c4 + 0) * 66 + row] = f2bf(v.x);
            T[(c4 + 1) * 66 + row] = f2bf(v.y);
            T[(c4 + 2) * 66 + row] = f2bf(v.z);
            T[(c4 + 3) * 66 + row] = f2bf(v.w);
        }
        __syncthreads();
        short* O = &Wqkvt[((size_t)g * 64 + orow) * 512 + kb * 64];
        *(bf16x8*)&O[oc16]     = *(const bf16x8*)&T[orow * 66 + oc16];
        *(bf16x8*)&O[oc16 + 8] = *(const bf16x8*)&T[orow * 66 + oc16 + 8];
    } else {
        const int jj = b - 1216, h = jj >> 3, nb = jj & 7;
        const float* W = Wo + (size_t)h * 64 * 512;
#pragma unroll
        for (int p = 0; p < 4; ++p) {
            const int row = p * 16 + rsub;
            const float4 v = *(const float4*)&W[(size_t)row * 512 + nb * 64 + c4];
            T[(c4 + 0) * 66 + row] = f2bf(v.x);
            T[(c4 + 1) * 66 + row] = f2bf(v.y);
            T[(c4 + 2) * 66 + row] = f2bf(v.z);
            T[(c4 + 3) * 66 + row] = f2bf(v.w);
        }
        __syncthreads();
        short* O = &Wot[((size_t)nb * 64 + orow) * 512 + h * 64];
        *(bf16x8*)&O[oc16]     = *(const bf16x8*)&T[orow * 66 + oc16];
        *(bf16x8*)&O[oc16 + 8] = *(const bf16x8*)&T[orow * 66 + oc16 + 8];
    }
}

// ---------------------------------------------------------------------------
// QKV projection. Q pre-scaled by QSCALE; Q,K stored [h][s][64]; V stored
// transposed [h][d][s] via LDS bounce.
// ---------------------------------------------------------------------------
__global__ __launch_bounds__(256) void qkv_gemm_kernel(
    const short* __restrict__ xb, const short* __restrict__ Wqkvt,
    short* __restrict__ Qg, short* __restrict__ Kg, short* __restrict__ Vtg)
{
    __shared__ short smem[16384];
    short* As = smem;
    short* Bs = smem + 8192;
    const int sblk = blockIdx.x, g = blockIdx.y;
    const int which = g >> 3, h = g & 7;
    const int t = threadIdx.x;
    const int wave = t >> 6, lane = t & 63, n16 = lane & 15, quad = lane >> 4;

    f32x4 acc[4] = {{0,0,0,0},{0,0,0,0},{0,0,0,0},{0,0,0,0}};
    gemm_mainloop_512(xb + (size_t)sblk * 64 * 512, Wqkvt + (size_t)g * 64 * 512,
                      As, Bs, acc, t);

    if (which < 2) {
        const float scale = (which == 0) ? QSCALE : 1.0f;
        short* O = ((which == 0) ? Qg : Kg) + (size_t)h * S_LEN * 64;
#pragma unroll
        for (int nt = 0; nt < 4; ++nt)
#pragma unroll
            for (int r = 0; r < 4; ++r) {
                const int s = sblk * 64 + wave * 16 + quad * 4 + r;
                O[(size_t)s * 64 + nt * 16 + n16] = f2bf(acc[nt][r] * scale);
            }
    } else {
        __syncthreads();
        short* Tr = smem;
#pragma unroll
        for (int nt = 0; nt < 4; ++nt)
#pragma unroll
            for (int r = 0; r < 4; ++r)
                Tr[(nt * 16 + n16) * 66 + wave * 16 + quad * 4 + r] = f2bf(acc[nt][r]);
        __syncthreads();
        short* O = Vtg + (size_t)h * 64 * S_LEN + sblk * 64;
        const int r4 = t >> 2, c16 = (t & 3) * 16;
        *(bf16x8*)&O[(size_t)r4 * S_LEN + c16]     = *(const bf16x8*)&Tr[r4 * 66 + c16];
        *(bf16x8*)&O[(size_t)r4 * S_LEN + c16 + 8] = *(const bf16x8*)&Tr[r4 * 66 + c16 + 8];
    }
}

// ---------------------------------------------------------------------------
// Output projection: vals bf16 [4096][512] x Wot[n][c] -> out fp32.
// ---------------------------------------------------------------------------
__global__ __launch_bounds__(256) void out_gemm_kernel(
    const short* __restrict__ vals, const short* __restrict__ Wot, float* __restrict__ out)
{
    __shared__ short smem[16384];
    short* As = smem;
    short* Bs = smem + 8192;
    const int sblk = blockIdx.x, g = blockIdx.y;
    const int t = threadIdx.x;
    const int wave = t >> 6, lane = t & 63, n16 = lane & 15, quad = lane >> 4;

    f32x4 acc[4] = {{0,0,0,0},{0,0,0,0},{0,0,0,0},{0,0,0,0}};
    gemm_mainloop_512(vals + (size_t)sblk * 64 * 512, Wot + (size_t)g * 64 * 512,
                      As, Bs, acc, t);

#pragma unroll
    for (int nt = 0; nt < 4; ++nt)
#pragma unroll
        for (int r = 0; r < 4; ++r) {
            const int s = sblk * 64 + wave * 16 + quad * 4 + r;
            out[(size_t)s * 512 + g * 64 + nt * 16 + n16] = acc[nt][r];
        }
}

// ---------------------------------------------------------------------------
// Flash attention, causal, static-reference softmax (p = exp2(sc): exact by
// shift-invariance; score bounds keep exp2 in fp32 range). Transposed MFMA:
//   Sc^T[key][q] = K x Q^T ;  O^T[v][q] += V^T x P ;  l via ones-row MFMA.
// Split-k: chunk c -> (qb, j), k-range [16j, min(16j+16, qb+1)).
// Partials written as COALESCED fp32 stores (no atomics, no memset):
//   Opart[slot h*160+c][v][q]  (64x64 tile, [v][q] so wave stores are 64B
//   segments),  Lpart[slot][q].  combine_norm sums <=4 slots.
// Grid 1280 = 8 h x 160 chunks; biggest chunks dispatch first (c reversed);
// h = id&7 spreads heads across XCDs.
// ---------------------------------------------------------------------------
__global__ __launch_bounds__(256, 4) void attn_kernel(
    const short* __restrict__ Qg, const short* __restrict__ Kg,
    const short* __restrict__ Vtg, float* __restrict__ Opart, float* __restrict__ Lpart)
{
    __shared__ short Ks[2][4096];
    __shared__ short Vs[2][4096];
    __shared__ short Ps[4096];             // [q][key^sw], row stride 64

    const int id = blockIdx.x;
    const int h  = id & 7;
    const int c  = 159 - (id >> 3);        // reversed: largest chunks first
    int qb, j;
    if (c < 16)      { qb = c;                    j = 0; }
    else if (c < 48) { qb = 16 + ((c - 16) >> 1); j = (c - 16) & 1; }
    else if (c < 96) { qb = 32 + (c - 48) / 3;    j = (c - 48) % 3; }
    else             { qb = 48 + ((c - 96) >> 2); j = (c - 96) & 3; }
    const int k0   = j * 16;
    const int kend = min(k0 + 16, qb + 1);

    const short* Kh  = Kg  + (size_t)h * S_LEN * 64;
    const short* Vth = Vtg + (size_t)h * 64 * S_LEN;

    const int t = threadIdx.x;
    const int wave = t >> 6, lane = t & 63, n16 = lane & 15, quad = lane >> 4;
    const int qrow = wave * 16 + n16;      // this lane's q (block-local)
    const int sw   = (qrow & 7) << 3;      // Ps key-index swizzle

    // Q B-fragments, loop-invariant, direct from global
    const short* Qr = Qg + (size_t)h * S_LEN * 64 + (size_t)(qb * 64 + qrow) * 64;
    const bf16x8 bq0 = *(const bf16x8*)&Qr[quad * 8];
    const bf16x8 bq1 = *(const bf16x8*)&Qr[32 + quad * 8];

    // all-ones A fragment for l accumulation (bf16 1.0 = 0x3F80)
    bf16x8 ones;
#pragma unroll
    for (int i = 0; i < 8; ++i) ones[i] = (short)0x3F80;

    f32x4 oacc[4] = {{0,0,0,0},{0,0,0,0},{0,0,0,0},{0,0,0,0}};
    f32x4 lacc = {0, 0, 0, 0};

    stage_tile(Kh + (size_t)k0 * 64 * 64, 64, Ks[0], t);
    stage_tile(Vth + k0 * 64, S_LEN, Vs[0], t);
    __syncthreads();

    for (int kb = k0; kb < kend; ++kb) {
        const int cur = (kb - k0) & 1;
        if (kb + 1 < kend) {               // async prefetch into other buffer
            stage_tile(Kh + (size_t)(kb + 1) * 64 * 64, 64, Ks[1 - cur], t);
            stage_tile(Vth + (kb + 1) * 64, S_LEN, Vs[1 - cur], t);
        }

        // Sc^T = K x Q^T
        f32x4 sc[4] = {{0,0,0,0},{0,0,0,0},{0,0,0,0},{0,0,0,0}};
#pragma unroll
        for (int kh = 0; kh < 2; ++kh) {
            const bf16x8 bq = kh ? bq1 : bq0;
#pragma unroll
            for (int mt = 0; mt < 4; ++mt) {
                const bf16x8 a = frag(Ks[cur], mt * 16 + n16, kh * 4 + quad);
                sc[mt] = __builtin_amdgcn_mfma_f32_16x16x32_bf16(a, bq, sc[mt], 0, 0, 0);
            }
        }

        if (kb == qb) {                    // causal mask, diagonal block only
#pragma unroll
            for (int mt = 0; mt < 4; ++mt) {
                const int key0 = mt * 16 + quad * 4;
#pragma unroll
                for (int r = 0; r < 4; ++r)
                    if (key0 + r > qrow) sc[mt][r] = -1e30f;
            }
        }

        // p = exp2(sc); packed bf16 straight to wave-local Ps
#pragma unroll
        for (int mt = 0; mt < 4; ++mt) {
            const float p0 = __builtin_amdgcn_exp2f(sc[mt][0]);
            const float p1 = __builtin_amdgcn_exp2f(sc[mt][1]);
            const float p2 = __builtin_amdgcn_exp2f(sc[mt][2]);
            const float p3 = __builtin_amdgcn_exp2f(sc[mt][3]);
            int2 pk; pk.x = pk2(p0, p1); pk.y = pk2(p2, p3);
            *(int2*)&Ps[qrow * 64 + ((mt * 16 + quad * 4) ^ sw)] = pk;
        }
        __builtin_amdgcn_wave_barrier();   // Ps writes stay above PV reads

        // O^T += V^T x P ; l += ones x P   (Ps rows wave-local, no barrier)
#pragma unroll
        for (int kh = 0; kh < 2; ++kh) {
            const bf16x8 bp = *(const bf16x8*)&Ps[qrow * 64 + ((kh * 32 + quad * 8) ^ sw)];
            lacc = __builtin_amdgcn_mfma_f32_16x16x32_bf16(ones, bp, lacc, 0, 0, 0);
#pragma unroll
            for (int mt = 0; mt < 4; ++mt) {
                const bf16x8 a = frag(Vs[cur], mt * 16 + n16, kh * 4 + quad);
                oacc[mt] = __builtin_amdgcn_mfma_f32_16x16x32_bf16(a, bp, oacc[mt], 0, 0, 0);
            }
        }
        __builtin_amdgcn_wave_barrier();
        __syncthreads();                   // buffer swap + prefetch drain
    }

    // epilogue: coalesced fp32 partial stores (wave -> 4x64B segments/instr)
    float* tileO = Opart + ((size_t)(h * 160 + c) << 12);
    float* tileL = Lpart + ((h * 160 + c) << 6);
    if (quad == 0) tileL[qrow] = lacc[0];  // every C row holds the same l[q]
#pragma unroll
    for (int mt = 0; mt < 4; ++mt)
#pragma unroll
        for (int r = 0; r < 4; ++r)
            tileO[((mt * 16 + quad * 4 + r) << 6) + qrow] = oacc[mt][r];
}

// ---------------------------------------------------------------------------
// Combine partials + normalize + transpose -> vals[s][h*64+v] bf16.
// One block per (h, qb): sum <=4 slot tiles [v][q], divide by summed l[q],
// bf16-pack into LDS [q][v] (stride 66), write 16B rows.
// ---------------------------------------------------------------------------
__global__ __launch_bounds__(256) void combine_norm_kernel(
    const float* __restrict__ Opart, const float* __restrict__ Lpart,
    short* __restrict__ vals)
{
    __shared__ short T[64 * 66];
    const int id = blockIdx.x;
    const int h = id & 7, qb = id >> 3;
    const int nj = (qb >> 4) + 1;
    int c0;
    if (qb < 16)      c0 = qb;
    else if (qb < 32) c0 = 16 + 2 * (qb - 16);
    else if (qb < 48) c0 = 48 + 3 * (qb - 32);
    else              c0 = 96 + 4 * (qb - 48);
    const int base = h * 160 + c0;

    const int t = threadIdx.x;
    const int q0 = (t & 15) * 4;
    const int vr = t >> 4;

    f32x4 L = {0, 0, 0, 0};
    for (int j = 0; j < nj; ++j)
        L += *(const f32x4*)&Lpart[((base + j) << 6) + q0];
    const f32x4 inv = {1.f / L[0], 1.f / L[1], 1.f / L[2], 1.f / L[3]};

#pragma unroll
    for (int pass = 0; pass < 4; ++pass) {
        const int v = vr + pass * 16;
        f32x4 s = {0, 0, 0, 0};
        for (int j = 0; j < nj; ++j)
            s += *(const f32x4*)&Opart[((size_t)(base + j) << 12) + (v << 6) + q0];
        T[(q0 + 0) * 66 + v] = f2bf(s[0] * inv[0]);
        T[(q0 + 1) * 66 + v] = f2bf(s[1] * inv[1]);
        T[(q0 + 2) * 66 + v] = f2bf(s[2] * inv[2]);
        T[(q0 + 3) * 66 + v] = f2bf(s[3] * inv[3]);
    }
    __syncthreads();
    const int q = t >> 2, vs = (t & 3) * 16;
    const size_t row = (size_t)(qb * 64 + q) * 512 + h * 64 + vs;
    *(bf16x8*)&vals[row]     = *(const bf16x8*)&T[q * 66 + vs];
    *(bf16x8*)&vals[row + 8] = *(const bf16x8*)&T[q * 66 + vs + 8];
}

// ---------------------------------------------------------------------------
// Workspace: shorts (xb 4MB | Wqkvt 1.5MB | Wot 0.5MB | Qg/Kg/Vtg 4MB ea |
// vals 4MB) = ~22MB, then fp32 Opart 20MB + Lpart 320KB  ~= 43 MB.
// ---------------------------------------------------------------------------
extern "C" void kernel_launch(void* const* d_in, const int* in_sizes, int n_in,
                              void* d_out, int out_size, void* d_ws, size_t ws_size,
                              hipStream_t stream)
{
    const float* x  = (const float*)d_in[0];
    const float* Wq = (const float*)d_in[1];
    const float* Wk = (const float*)d_in[2];
    const float* Wv = (const float*)d_in[3];
    const float* Wo = (const float*)d_in[4];
    float* out = (float*)d_out;

    short* xb    = (short*)d_ws;
    short* Wqkvt = xb + 2097152;
    short* Wot   = Wqkvt + 786432;
    short* Qg    = Wot + 262144;
    short* Kg    = Qg + 2097152;
    short* Vtg   = Kg + 2097152;
    short* vals  = Vtg + 2097152;
    float* Opart = (float*)(vals + 2097152);
    float* Lpart = Opart + (size_t)1280 * 4096;

    prep_kernel<<<1280, 256, 0, stream>>>(x, Wq, Wk, Wv, Wo, xb, Wqkvt, Wot);
    qkv_gemm_kernel<<<dim3(64, 24), 256, 0, stream>>>(xb, Wqkvt, Qg, Kg, Vtg);
    attn_kernel<<<1280, 256, 0, stream>>>(Qg, Kg, Vtg, Opart, Lpart);
    combine_norm_kernel<<<512, 256, 0, stream>>>(Opart, Lpart, vals);
    out_gemm_kernel<<<dim3(64, 8), 256, 0, stream>>>(vals, Wot, out);
}